// Round 10
// baseline (252.088 us; speedup 1.0000x reference)
//
#include <hip/hip_runtime.h>

// SpikingNeuralNetwork: fc1 (split-bf16x3 MFMA GEMM, fused LIF scan) + sparse fc2.
// R10: occupancy-first. 256x128 block tile, 8 waves (4M x 2N), wave tile 64x64
// (acc=64 VGPR), BK=16, tri-buffered 72KB LDS, launch_bounds(512,4) -> 2 blocks/CU
// (16 waves/CU). Minimal sync: counted vmcnt(3)+barrier per kt; compiler schedules
// ds_read<->MFMA; cross-block TLP fills the stalls.

typedef __attribute__((ext_vector_type(16))) float f32x16;
typedef __attribute__((ext_vector_type(8))) short s16x8;

#define GPTR(p) ((const __attribute__((address_space(1))) void*)(p))
#define SPTR(p) ((__attribute__((address_space(3))) void*)(p))

static constexpr int Bsz = 64, Tsz = 256, Isz = 1024, Hsz = 2048, Osz = 1024;
static constexpr int BK = 16;          // fp32-k per K-tile
static constexpr int NKT = Isz / BK;   // 64
static constexpr int NB = 128;         // h columns per block
// regions (ushort el) within one 24KB buffer: Ah[256][16], Al[256][16], B(h+l)[2x128][16]
static constexpr int AL_OFF = 4096, B_OFF = 8192;
static constexpr int BUFEL = 12288;    // 24KB; x3 = 72KB
static constexpr int ST = 68;          // scan [col][t] stride (f32), 16B-aligned
static constexpr int LDS_USHORTS = 3 * BUFEL;  // 73728 B; scan (128*68*4=34.8KB) fits

__device__ __forceinline__ unsigned short f2bf(float f) {
  unsigned u = __float_as_uint(f);
  u += 0x7FFFu + ((u >> 16) & 1u);
  return (unsigned short)(u >> 16);
}
__device__ __forceinline__ float bf2f(unsigned short h) {
  return __uint_as_float(((unsigned)h) << 16);
}

// ---------------- kernel 1: split x into hi/lo bf16 ----------------
__global__ void split_x_kernel(const float* __restrict__ x,
                               unsigned short* __restrict__ hi,
                               unsigned short* __restrict__ lo) {
  const long i = (long)blockIdx.x * 256 + threadIdx.x;
  const float4 v = ((const float4*)x)[i];
  const unsigned short hx = f2bf(v.x), hy = f2bf(v.y), hz = f2bf(v.z), hw = f2bf(v.w);
  ushort4 H, L;
  H.x = hx; H.y = hy; H.z = hz; H.w = hw;
  L.x = f2bf(v.x - bf2f(hx));
  L.y = f2bf(v.y - bf2f(hy));
  L.z = f2bf(v.z - bf2f(hz));
  L.w = f2bf(v.w - bf2f(hw));
  ((ushort4*)hi)[i] = H;
  ((ushort4*)lo)[i] = L;
}

// ------- kernel 2: W1 [I][H] -> transposed bf16 hi/lo [H][I] -------
__global__ void w1_transpose_split_kernel(const float* __restrict__ W1,
                                          unsigned short* __restrict__ wh,
                                          unsigned short* __restrict__ wl) {
  __shared__ float tile[32][33];
  const int h0 = blockIdx.x * 32;
  const int i0 = blockIdx.y * 32;
  const int c = threadIdx.x & 31;
  const int r4 = threadIdx.x >> 5;
#pragma unroll
  for (int s = 0; s < 4; ++s) {
    const int r = r4 + s * 8;
    tile[r][c] = W1[(long)(i0 + r) * Hsz + h0 + c];
  }
  __syncthreads();
#pragma unroll
  for (int s = 0; s < 4; ++s) {
    const int hr = r4 + s * 8;
    const float v = tile[c][hr];
    const unsigned short hh = f2bf(v);
    wh[(long)(h0 + hr) * Isz + i0 + c] = hh;
    wl[(long)(h0 + hr) * Isz + i0 + c] = f2bf(v - bf2f(hh));
  }
}

// ---- kernel 3: fused GEMM1 (split-bf16x3, 32x32x16 MFMA) + LIF scan ----
// grid (16 hblk, 64 b), 512 threads = 8 waves (4M x 2N); wave tile 64x64.
__global__ __launch_bounds__(512, 4) void gemm1_scan_kernel(
    const unsigned short* __restrict__ xh, const unsigned short* __restrict__ xl,
    const unsigned short* __restrict__ wth, const unsigned short* __restrict__ wtl,
    const float* __restrict__ b1, float* __restrict__ spk) {
  __shared__ __align__(16) unsigned short lds[LDS_USHORTS];  // 72KB -> 2 blocks/CU

  const int tid = threadIdx.x;
  const int l = tid & 63;
  const int w = tid >> 6;
  const int wm = w >> 1;  // 0..3 (M: 64 t-rows each)
  const int wn = w & 1;   // 0..1 (N: 64 h-cols each)
  const int b = blockIdx.y;
  const int hb = blockIdx.x * NB;

  // --- staging sources: row-major [R][16] regions, 2 threads/row (16B each) ---
  const int arow = tid >> 1;                 // 0..255
  const int brow = (tid >> 1) & 127;         // 0..127 for both halves
  const int ch8 = (tid & 1) * 8;
  const unsigned short* gAh = xh + (long)(b * Tsz + arow) * Isz + ch8;
  const unsigned short* gAl = xl + (long)(b * Tsz + arow) * Isz + ch8;
  // B region holds Bh rows (tid<256) then Bl rows (tid>=256) -> one instr stages both
  const unsigned short* gB = ((tid < 256) ? wth : wtl) + (long)(hb + brow) * Isz + ch8;

  // 3 global_load_lds per K-tile (each: 512 thr x 16B = 8KB region)
#define STG(Q, KT) do {                                                                   \
    unsigned short* d_ = lds + (Q) * BUFEL + tid * 8;                                     \
    __builtin_amdgcn_global_load_lds(GPTR(gAh + (long)(KT) * BK), SPTR(d_), 16, 0, 0);    \
    __builtin_amdgcn_global_load_lds(GPTR(gAl + (long)(KT) * BK), SPTR(d_ + AL_OFF), 16, 0, 0); \
    __builtin_amdgcn_global_load_lds(GPTR(gB + (long)(KT) * BK), SPTR(d_ + B_OFF), 16, 0, 0);   \
  } while (0)

  // --- fragment read offsets (ushort el): row = base + (l&31), k = (l>>5)*8 + j ---
  const int lr = l & 31;
  const int kc = (l >> 5) * 8;
  const int aoff0 = (wm * 64 + lr) * 16 + kc;          // Ah mi=0 (+512 for mi=1)
  const int boff0 = B_OFF + (wn * 64 + lr) * 16 + kc;  // Bh ni=0 (+512 ni=1; +2048 Bl)

  f32x16 acc[2][2];
#pragma unroll
  for (int i = 0; i < 2; ++i)
#pragma unroll
    for (int j = 0; j < 2; ++j) acc[i][j] = (f32x16)(0.f);

#define MM(MI, NI, AF, BF) \
  acc[MI][NI] = __builtin_amdgcn_mfma_f32_32x32x16_bf16(AF, BF, acc[MI][NI], 0, 0, 0)

  // --- prologue: stage tiles 0 (buf0) and 1 (buf1); wait tile 0; sync ---
  STG(0, 0);
  STG(1, 1);
  asm volatile("s_waitcnt vmcnt(3)" ::: "memory");  // tile 0 landed; tile 1 in flight
  __builtin_amdgcn_s_barrier();

  for (int kt = 0; kt < NKT; ++kt) {
    const int q = kt % 3;
    const unsigned short* p = lds + q * BUFEL;

    // stage kt+2 first (max latency cover: waited-for loads are ~2 iters old)
    if (kt + 2 < NKT) {
      const int qn = (q >= 1) ? q - 1 : 2;  // (q+2)%3
      STG(qn, kt + 2);
    }

    // fragment reads (compiler inserts fine-grained lgkmcnt before MFMA uses)
    s16x8 Ah0 = *(const s16x8*)(p + aoff0);
    s16x8 Ah1 = *(const s16x8*)(p + aoff0 + 512);
    s16x8 Al0 = *(const s16x8*)(p + AL_OFF + aoff0);
    s16x8 Al1 = *(const s16x8*)(p + AL_OFF + aoff0 + 512);
    s16x8 Bh0 = *(const s16x8*)(p + boff0);
    s16x8 Bh1 = *(const s16x8*)(p + boff0 + 512);
    s16x8 Bl0 = *(const s16x8*)(p + boff0 + 2048);
    s16x8 Bl1 = *(const s16x8*)(p + boff0 + 2048 + 512);

    // 12 MFMA: hihi + hilo + lohi
    MM(0, 0, Ah0, Bh0); MM(0, 1, Ah0, Bh1);
    MM(1, 0, Ah1, Bh0); MM(1, 1, Ah1, Bh1);
    MM(0, 0, Ah0, Bl0); MM(0, 1, Ah0, Bl1);
    MM(1, 0, Ah1, Bl0); MM(1, 1, Ah1, Bl1);
    MM(0, 0, Al0, Bh0); MM(0, 1, Al0, Bh1);
    MM(1, 0, Al1, Bh0); MM(1, 1, Al1, Bh1);

    // counted never-drain: steady outstanding = {kt+1:3, kt+2:3}; next iter needs kt+1
    if (kt < NKT - 2) asm volatile("s_waitcnt vmcnt(3)" ::: "memory");
    else              asm volatile("s_waitcnt vmcnt(0)" ::: "memory");
    __builtin_amdgcn_s_barrier();  // cross-wave: next buffer landed for ALL waves
  }

  // ---- LIF scan: 4 rounds x 64 timesteps; [col][ST=68] layout (34.8KB) ----
  __syncthreads();
  float* scanbuf = reinterpret_cast<float*>(lds);
  float memv = 0.f;
  int fired = 0;
  const float b1v = (tid < NB) ? b1[hb + tid] : 0.f;

  for (int rnd = 0; rnd < 4; ++rnd) {
    if (wm == rnd) {
      // C/D 32x32: col = l&31, t-local = mi*32 + (r&3) + 8*(r>>2) + 4*(l>>5)
#pragma unroll
      for (int mi = 0; mi < 2; ++mi)
#pragma unroll
        for (int ni = 0; ni < 2; ++ni) {
          const int col = wn * 64 + ni * 32 + lr;
          float* dst = scanbuf + col * ST + mi * 32 + 4 * (l >> 5);
#pragma unroll
          for (int rq = 0; rq < 4; ++rq) {
            float4 v;
            v.x = acc[mi][ni][rq * 4 + 0];
            v.y = acc[mi][ni][rq * 4 + 1];
            v.z = acc[mi][ni][rq * 4 + 2];
            v.w = acc[mi][ni][rq * 4 + 3];
            *reinterpret_cast<float4*>(dst + 8 * rq) = v;
          }
        }
    }
    __syncthreads();
    if (tid < NB) {
      const float* src = scanbuf + tid * ST;
      float4 cur = *reinterpret_cast<const float4*>(src);
      for (int t0 = 0; t0 < 64; t0 += 4) {
        const int tn = (t0 + 4 < 64) ? t0 + 4 : t0;
        const float4 nxt = *reinterpret_cast<const float4*>(src + tn);
        float c;
        c = cur.x + b1v; memv = memv * 0.9f + c * 0.1f; fired = memv > 1.0f; if (fired) memv = 0.f;
        c = cur.y + b1v; memv = memv * 0.9f + c * 0.1f; fired = memv > 1.0f; if (fired) memv = 0.f;
        c = cur.z + b1v; memv = memv * 0.9f + c * 0.1f; fired = memv > 1.0f; if (fired) memv = 0.f;
        c = cur.w + b1v; memv = memv * 0.9f + c * 0.1f; fired = memv > 1.0f; if (fired) memv = 0.f;
        cur = nxt;
      }
    }
    __syncthreads();
  }
  if (tid < NB) spk[(long)b * Hsz + hb + tid] = fired ? 1.0f : 0.0f;
}

// ------- kernel 4: out = spk @ W2 + b2, exploiting spike sparsity -------
__global__ void gemm2_kernel(const float* __restrict__ spk, const float* __restrict__ W2,
                             const float* __restrict__ b2, float* __restrict__ out) {
  __shared__ int s_cnt[256];
  __shared__ int s_off[257];
  __shared__ int s_list[Hsz];
  const int b = blockIdx.x;
  const int tid = threadIdx.x;
  int hs[8];
  int c = 0;
#pragma unroll
  for (int e = 0; e < 8; ++e) {
    const int h = tid * 8 + e;
    if (spk[(long)b * Hsz + h] > 0.5f) hs[c++] = h;
  }
  s_cnt[tid] = c;
  __syncthreads();
  if (tid == 0) {
    int s = 0;
    for (int i = 0; i < 256; ++i) { s_off[i] = s; s += s_cnt[i]; }
    s_off[256] = s;
  }
  __syncthreads();
  {
    const int base = s_off[tid];
    for (int i = 0; i < c; ++i) s_list[base + i] = hs[i];
  }
  __syncthreads();
  const int total = s_off[256];
#pragma unroll
  for (int q = 0; q < 4; ++q) {
    const int o = q * 256 + tid;
    float v = b2[o];
    for (int i = 0; i < total; ++i) v += W2[(long)s_list[i] * Osz + o];
    out[(long)b * Osz + o] = v;
  }
}

extern "C" void kernel_launch(void* const* d_in, const int* in_sizes, int n_in,
                              void* d_out, int out_size, void* d_ws, size_t ws_size,
                              hipStream_t stream) {
  const float* x = (const float*)d_in[0];
  const float* W1 = (const float*)d_in[1];
  const float* b1 = (const float*)d_in[2];
  const float* W2 = (const float*)d_in[3];
  const float* b2 = (const float*)d_in[4];
  float* out = (float*)d_out;

  unsigned short* xh = (unsigned short*)d_ws;           // [16384][1024] bf16
  unsigned short* xl = xh + (long)Bsz * Tsz * Isz;
  unsigned short* wh = xl + (long)Bsz * Tsz * Isz;      // [2048][1024] (W1^T)
  unsigned short* wl = wh + (long)Hsz * Isz;
  float* spk = (float*)(wl + (long)Hsz * Isz);          // [64][2048]

  split_x_kernel<<<(Bsz * Tsz * Isz) / (256 * 4), 256, 0, stream>>>(x, xh, xl);
  w1_transpose_split_kernel<<<dim3(Hsz / 32, Isz / 32), 256, 0, stream>>>(W1, wh, wl);
  gemm1_scan_kernel<<<dim3(Hsz / NB, Bsz), 512, 0, stream>>>(xh, xl, wh, wl, b1, spk);
  gemm2_kernel<<<Bsz, 256, 0, stream>>>(spk, W2, b2, out);
}

// Round 11
// 250.287 us; speedup vs baseline: 1.0072x; 1.0072x over previous
//
#include <hip/hip_runtime.h>

// SpikingNeuralNetwork: fc1 (split-bf16x3 MFMA GEMM, fused LIF scan) + sparse fc2.
// R11: two INDEPENDENT 4-wave blocks per CU (separate barrier groups -> pipe
// overlap), wave tile 128x64 (near-min LDS traffic at 2 waves/SIMD), 256x128
// block tile, BK=16 tri-buffered 72KB LDS, counted vmcnt(6) never-drain.

typedef __attribute__((ext_vector_type(16))) float f32x16;
typedef __attribute__((ext_vector_type(8))) short s16x8;

#define GPTR(p) ((const __attribute__((address_space(1))) void*)(p))
#define SPTR(p) ((__attribute__((address_space(3))) void*)(p))

static constexpr int Bsz = 64, Tsz = 256, Isz = 1024, Hsz = 2048, Osz = 1024;
static constexpr int BK = 16;          // fp32-k per K-tile
static constexpr int NKT = Isz / BK;   // 64
static constexpr int NB = 128;         // h columns per block
// regions (ushort el): Ah[256][16]=4096, Al[256][16]=4096, Bh[128][16]=2048, Bl=2048
static constexpr int AL_OFF = 4096, BH_OFF = 8192, BL_OFF = 10240;
static constexpr int BUFEL = 12288;    // 24KB; x3 = 72KB -> 2 blocks/CU
static constexpr int ST = 132;         // scan [col][t] stride (f32)
static constexpr int LDS_USHORTS = 3 * BUFEL;  // 73728 B; scan 128*132*4=67.6KB fits

__device__ __forceinline__ unsigned short f2bf(float f) {
  unsigned u = __float_as_uint(f);
  u += 0x7FFFu + ((u >> 16) & 1u);
  return (unsigned short)(u >> 16);
}
__device__ __forceinline__ float bf2f(unsigned short h) {
  return __uint_as_float(((unsigned)h) << 16);
}

// ---------------- kernel 1: split x into hi/lo bf16 ----------------
__global__ void split_x_kernel(const float* __restrict__ x,
                               unsigned short* __restrict__ hi,
                               unsigned short* __restrict__ lo) {
  const long i = (long)blockIdx.x * 256 + threadIdx.x;
  const float4 v = ((const float4*)x)[i];
  const unsigned short hx = f2bf(v.x), hy = f2bf(v.y), hz = f2bf(v.z), hw = f2bf(v.w);
  ushort4 H, L;
  H.x = hx; H.y = hy; H.z = hz; H.w = hw;
  L.x = f2bf(v.x - bf2f(hx));
  L.y = f2bf(v.y - bf2f(hy));
  L.z = f2bf(v.z - bf2f(hz));
  L.w = f2bf(v.w - bf2f(hw));
  ((ushort4*)hi)[i] = H;
  ((ushort4*)lo)[i] = L;
}

// ------- kernel 2: W1 [I][H] -> transposed bf16 hi/lo [H][I] -------
__global__ void w1_transpose_split_kernel(const float* __restrict__ W1,
                                          unsigned short* __restrict__ wh,
                                          unsigned short* __restrict__ wl) {
  __shared__ float tile[32][33];
  const int h0 = blockIdx.x * 32;
  const int i0 = blockIdx.y * 32;
  const int c = threadIdx.x & 31;
  const int r4 = threadIdx.x >> 5;
#pragma unroll
  for (int s = 0; s < 4; ++s) {
    const int r = r4 + s * 8;
    tile[r][c] = W1[(long)(i0 + r) * Hsz + h0 + c];
  }
  __syncthreads();
#pragma unroll
  for (int s = 0; s < 4; ++s) {
    const int hr = r4 + s * 8;
    const float v = tile[c][hr];
    const unsigned short hh = f2bf(v);
    wh[(long)(h0 + hr) * Isz + i0 + c] = hh;
    wl[(long)(h0 + hr) * Isz + i0 + c] = f2bf(v - bf2f(hh));
  }
}

// ---- kernel 3: fused GEMM1 (split-bf16x3, 32x32x16 MFMA) + LIF scan ----
// grid (16 hblk, 64 b), 256 threads = 4 waves (2M x 2N); wave tile 128x64.
// 2 blocks/CU with independent barriers -> MFMA of one fills LDS stalls of other.
__global__ __launch_bounds__(256, 2) void gemm1_scan_kernel(
    const unsigned short* __restrict__ xh, const unsigned short* __restrict__ xl,
    const unsigned short* __restrict__ wth, const unsigned short* __restrict__ wtl,
    const float* __restrict__ b1, float* __restrict__ spk) {
  __shared__ __align__(16) unsigned short lds[LDS_USHORTS];  // 72KB

  const int tid = threadIdx.x;
  const int l = tid & 63;
  const int w = tid >> 6;
  const int wm = w >> 1;  // 0..1 (M: 128 t-rows each)
  const int wn = w & 1;   // 0..1 (N: 64 h-cols each)
  const int b = blockIdx.y;
  const int hb = blockIdx.x * NB;

  // --- staging sources: row-major [R][16] regions, 2 threads/row (16B each) ---
  const int srow = tid >> 1;            // 0..127
  const int ch8 = (tid & 1) * 8;
  const unsigned short* gAh = xh + (long)(b * Tsz + srow) * Isz + ch8;   // +128*Isz for hi rows
  const unsigned short* gAl = xl + (long)(b * Tsz + srow) * Isz + ch8;
  const unsigned short* gBh = wth + (long)(hb + srow) * Isz + ch8;
  const unsigned short* gBl = wtl + (long)(hb + srow) * Isz + ch8;

  // 6 global_load_lds per K-tile (each: 256 thr x 16B = 4KB region)
#define STG(Q, KT) do {                                                                   \
    unsigned short* d_ = lds + (Q) * BUFEL + tid * 8;                                     \
    __builtin_amdgcn_global_load_lds(GPTR(gAh + (long)(KT) * BK), SPTR(d_), 16, 0, 0);    \
    __builtin_amdgcn_global_load_lds(GPTR(gAh + 128 * Isz + (long)(KT) * BK), SPTR(d_ + 2048), 16, 0, 0); \
    __builtin_amdgcn_global_load_lds(GPTR(gAl + (long)(KT) * BK), SPTR(d_ + AL_OFF), 16, 0, 0);           \
    __builtin_amdgcn_global_load_lds(GPTR(gAl + 128 * Isz + (long)(KT) * BK), SPTR(d_ + AL_OFF + 2048), 16, 0, 0); \
    __builtin_amdgcn_global_load_lds(GPTR(gBh + (long)(KT) * BK), SPTR(d_ + BH_OFF), 16, 0, 0);           \
    __builtin_amdgcn_global_load_lds(GPTR(gBl + (long)(KT) * BK), SPTR(d_ + BL_OFF), 16, 0, 0);           \
  } while (0)

  // --- fragment read offsets: row = base + mi*32 + (l&31), k-chunk = (l>>5)*8 ---
  const int lr = l & 31;
  const int kc = (l >> 5) * 8;
  const int aoff = (wm * 128 + lr) * 16 + kc;           // + mi*512
  const int boff = BH_OFF + (wn * 64 + lr) * 16 + kc;   // + ni*512; +2048 for Bl

  f32x16 acc[4][2];
#pragma unroll
  for (int i = 0; i < 4; ++i)
#pragma unroll
    for (int j = 0; j < 2; ++j) acc[i][j] = (f32x16)(0.f);

#define MM(MI, NI, AF, BF) \
  acc[MI][NI] = __builtin_amdgcn_mfma_f32_32x32x16_bf16(AF, BF, acc[MI][NI], 0, 0, 0)

  // --- prologue: stage tiles 0 (buf0) and 1 (buf1); wait tile 0; sync ---
  STG(0, 0);
  STG(1, 1);
  asm volatile("s_waitcnt vmcnt(6)" ::: "memory");  // tile 0 landed; tile 1 in flight
  __builtin_amdgcn_s_barrier();

  for (int kt = 0; kt < NKT; ++kt) {
    const int q = kt % 3;
    const unsigned short* p = lds + q * BUFEL;

    // stage kt+2 first (max latency cover)
    if (kt + 2 < NKT) {
      const int qn = (q >= 1) ? q - 1 : 2;  // (q+2)%3
      STG(qn, kt + 2);
    }

    // fragment reads (compiler inserts fine-grained lgkmcnt before MFMA uses)
    s16x8 Ah0 = *(const s16x8*)(p + aoff);
    s16x8 Ah1 = *(const s16x8*)(p + aoff + 512);
    s16x8 Ah2 = *(const s16x8*)(p + aoff + 1024);
    s16x8 Ah3 = *(const s16x8*)(p + aoff + 1536);
    s16x8 Al0 = *(const s16x8*)(p + AL_OFF + aoff);
    s16x8 Al1 = *(const s16x8*)(p + AL_OFF + aoff + 512);
    s16x8 Al2 = *(const s16x8*)(p + AL_OFF + aoff + 1024);
    s16x8 Al3 = *(const s16x8*)(p + AL_OFF + aoff + 1536);
    s16x8 Bh0 = *(const s16x8*)(p + boff);
    s16x8 Bh1 = *(const s16x8*)(p + boff + 512);
    s16x8 Bl0 = *(const s16x8*)(p + boff + 2048);
    s16x8 Bl1 = *(const s16x8*)(p + boff + 2048 + 512);

    // 24 MFMA: hihi + hilo + lohi over 4 mi x 2 ni
    MM(0, 0, Ah0, Bh0); MM(0, 1, Ah0, Bh1);
    MM(1, 0, Ah1, Bh0); MM(1, 1, Ah1, Bh1);
    MM(2, 0, Ah2, Bh0); MM(2, 1, Ah2, Bh1);
    MM(3, 0, Ah3, Bh0); MM(3, 1, Ah3, Bh1);
    MM(0, 0, Ah0, Bl0); MM(0, 1, Ah0, Bl1);
    MM(1, 0, Ah1, Bl0); MM(1, 1, Ah1, Bl1);
    MM(2, 0, Ah2, Bl0); MM(2, 1, Ah2, Bl1);
    MM(3, 0, Ah3, Bl0); MM(3, 1, Ah3, Bl1);
    MM(0, 0, Al0, Bh0); MM(0, 1, Al0, Bh1);
    MM(1, 0, Al1, Bh0); MM(1, 1, Al1, Bh1);
    MM(2, 0, Al2, Bh0); MM(2, 1, Al2, Bh1);
    MM(3, 0, Al3, Bh0); MM(3, 1, Al3, Bh1);

    // counted never-drain: steady outstanding = {kt+1:6, kt+2:6}; next iter needs kt+1
    if (kt < NKT - 2) asm volatile("s_waitcnt vmcnt(6)" ::: "memory");
    else              asm volatile("s_waitcnt vmcnt(0)" ::: "memory");
    __builtin_amdgcn_s_barrier();  // cross-wave: next buffer landed for ALL waves
  }

  // ---- LIF scan: 2 rounds x 128 timesteps; [col][ST=132] layout (67.6KB) ----
  __syncthreads();
  float* scanbuf = reinterpret_cast<float*>(lds);
  float memv = 0.f;
  int fired = 0;
  const float b1v = (tid < NB) ? b1[hb + tid] : 0.f;

  for (int rnd = 0; rnd < 2; ++rnd) {
    if (wm == rnd) {
      // C/D 32x32: col = l&31, t-local = mi*32 + (r&3) + 8*(r>>2) + 4*(l>>5)
#pragma unroll
      for (int mi = 0; mi < 4; ++mi)
#pragma unroll
        for (int ni = 0; ni < 2; ++ni) {
          const int col = wn * 64 + ni * 32 + lr;
          float* dst = scanbuf + col * ST + mi * 32 + 4 * (l >> 5);
#pragma unroll
          for (int rq = 0; rq < 4; ++rq) {
            float4 v;
            v.x = acc[mi][ni][rq * 4 + 0];
            v.y = acc[mi][ni][rq * 4 + 1];
            v.z = acc[mi][ni][rq * 4 + 2];
            v.w = acc[mi][ni][rq * 4 + 3];
            *reinterpret_cast<float4*>(dst + 8 * rq) = v;
          }
        }
    }
    __syncthreads();
    if (tid < NB) {
      const float* src = scanbuf + tid * ST;
      float4 cur = *reinterpret_cast<const float4*>(src);
      for (int t0 = 0; t0 < 128; t0 += 4) {
        const int tn = (t0 + 4 < 128) ? t0 + 4 : t0;
        const float4 nxt = *reinterpret_cast<const float4*>(src + tn);
        float c;
        c = cur.x + b1v; memv = memv * 0.9f + c * 0.1f; fired = memv > 1.0f; if (fired) memv = 0.f;
        c = cur.y + b1v; memv = memv * 0.9f + c * 0.1f; fired = memv > 1.0f; if (fired) memv = 0.f;
        c = cur.z + b1v; memv = memv * 0.9f + c * 0.1f; fired = memv > 1.0f; if (fired) memv = 0.f;
        c = cur.w + b1v; memv = memv * 0.9f + c * 0.1f; fired = memv > 1.0f; if (fired) memv = 0.f;
        cur = nxt;
      }
    }
    __syncthreads();
  }
  if (tid < NB) spk[(long)b * Hsz + hb + tid] = fired ? 1.0f : 0.0f;
}

// ------- kernel 4: out = spk @ W2 + b2, exploiting spike sparsity -------
__global__ void gemm2_kernel(const float* __restrict__ spk, const float* __restrict__ W2,
                             const float* __restrict__ b2, float* __restrict__ out) {
  __shared__ int s_cnt[256];
  __shared__ int s_off[257];
  __shared__ int s_list[Hsz];
  const int b = blockIdx.x;
  const int tid = threadIdx.x;
  int hs[8];
  int c = 0;
#pragma unroll
  for (int e = 0; e < 8; ++e) {
    const int h = tid * 8 + e;
    if (spk[(long)b * Hsz + h] > 0.5f) hs[c++] = h;
  }
  s_cnt[tid] = c;
  __syncthreads();
  if (tid == 0) {
    int s = 0;
    for (int i = 0; i < 256; ++i) { s_off[i] = s; s += s_cnt[i]; }
    s_off[256] = s;
  }
  __syncthreads();
  {
    const int base = s_off[tid];
    for (int i = 0; i < c; ++i) s_list[base + i] = hs[i];
  }
  __syncthreads();
  const int total = s_off[256];
#pragma unroll
  for (int q = 0; q < 4; ++q) {
    const int o = q * 256 + tid;
    float v = b2[o];
    for (int i = 0; i < total; ++i) v += W2[(long)s_list[i] * Osz + o];
    out[(long)b * Osz + o] = v;
  }
}

extern "C" void kernel_launch(void* const* d_in, const int* in_sizes, int n_in,
                              void* d_out, int out_size, void* d_ws, size_t ws_size,
                              hipStream_t stream) {
  const float* x = (const float*)d_in[0];
  const float* W1 = (const float*)d_in[1];
  const float* b1 = (const float*)d_in[2];
  const float* W2 = (const float*)d_in[3];
  const float* b2 = (const float*)d_in[4];
  float* out = (float*)d_out;

  unsigned short* xh = (unsigned short*)d_ws;           // [16384][1024] bf16
  unsigned short* xl = xh + (long)Bsz * Tsz * Isz;
  unsigned short* wh = xl + (long)Bsz * Tsz * Isz;      // [2048][1024] (W1^T)
  unsigned short* wl = wh + (long)Hsz * Isz;
  float* spk = (float*)(wl + (long)Hsz * Isz);          // [64][2048]

  split_x_kernel<<<(Bsz * Tsz * Isz) / (256 * 4), 256, 0, stream>>>(x, xh, xl);
  w1_transpose_split_kernel<<<dim3(Hsz / 32, Isz / 32), 256, 0, stream>>>(W1, wh, wl);
  gemm1_scan_kernel<<<dim3(Hsz / NB, Bsz), 256, 0, stream>>>(xh, xl, wh, wl, b1, spk);
  gemm2_kernel<<<Bsz, 256, 0, stream>>>(spk, W2, b2, out);
}